// Round 3
// baseline (573.693 us; speedup 1.0000x reference)
//
#include <hip/hip_runtime.h>
#include <math.h>

#define W 128
#define NANG 128
#define SZ 128
#define NV 8
#define NROWS 2048          // B*C*H
#define K_DIM 1024          // NV * W
#define NPIX 16384          // SZ * SZ
#define OUT_SCALE 0.012271846303085130f   // pi / 256

typedef _Float16 f16x8 __attribute__((ext_vector_type(8)));
typedef _Float16 f16x4 __attribute__((ext_vector_type(4)));
typedef float    f32x4 __attribute__((ext_vector_type(4)));

// ws layout:
//   [36864, +4MiB)  : Pf  f16 [2048 r][8 v][128 t]
//   [.., +32MiB)    : Wv  f16 [16384 pix][1024 k]
#define PF_OFF 36864
#define WV_OFF (36864 + (size_t)NROWS * K_DIM * 2)

struct Ptrs8 { const float* p[8]; };

__device__ __forceinline__ void glds16(const void* g, void* l) {
    __builtin_amdgcn_global_load_lds(
        (const __attribute__((address_space(1))) void*)g,
        (__attribute__((address_space(3))) void*)l, 16, 0, 0);
}

// ---- kernel 1: fused prep ----
// blocks [0,256): filter-GEMM  Pf[(r,v)][t] = sum_s In[v][r][s] * C[t][s]
//   with the circulant C built in LDS from locally-computed filter taps.
// blocks [256,2304): Wv[pixel][k] fused angle-lerp x detector-lerp weights,
//   with the cos/sin table computed locally.
#define FS_A 136   // padded LDS row stride (halfs): +8 -> 2-way bank alias only
#define PREP_FG_BLOCKS 256

union PrepLds {
    struct {                        // fgemm role (52.7 KB)
        _Float16 sA[64 * FS_A];
        _Float16 sB[128 * FS_A];
        float    kl[W];
    } fg;
    struct {                        // wv role (33.8 KB)
        float  wrow[8 * K_DIM];
        float2 cst[NANG];
    } wv;
};

__global__ __launch_bounds__(256)
void k_prep(Ptrs8 in, _Float16* __restrict__ pf, _Float16* __restrict__ wv) {
    __shared__ PrepLds u;
    const int tid = threadIdx.x;

    if (blockIdx.x < PREP_FG_BLOCKS) {
        // ================= filter-GEMM role =================
        const int blk  = blockIdx.x;
        const int lane = tid & 63, wave = tid >> 6;
        const int fr = lane & 15, fg = lane >> 4;

        if (tid < W) {
            const int d = tid;
            const float w0 = 6.283185307179586f / (float)W * (float)d;
            float s = 0.f;
            for (int f = 1; f < 64; ++f)
                s = fmaf((float)f, __cosf(w0 * (float)f), s);
            s = 2.f * s + 64.f * ((d & 1) ? -1.f : 1.f);
            u.fg.kl[d] = s * (1.f / (float)(W * W));
        }
        {
            const int i   = tid >> 5;          // row-within-view-group 0..7
            const int pos = (tid & 31) * 4;    // f32 position 0..124
#pragma unroll
            for (int v = 0; v < NV; ++v) {
                float4 x = *(const float4*)(in.p[v] + (size_t)(blk * 8 + i) * W + pos);
                f16x4 h = { (_Float16)x.x, (_Float16)x.y, (_Float16)x.z, (_Float16)x.w };
                *(f16x4*)&u.fg.sA[(i * 8 + v) * FS_A + pos] = h;
            }
        }
        __syncthreads();
        for (int e = tid; e < W * W; e += 256) {
            const int t = e >> 7, s = e & 127;
            u.fg.sB[t * FS_A + s] = (_Float16)u.fg.kl[(t - s) & (W - 1)];
        }
        __syncthreads();

        f32x4 acc[8] = {};
#pragma unroll
        for (int kb = 0; kb < W; kb += 32) {
            f16x8 af = *(const f16x8*)&u.fg.sA[(wave * 16 + fr) * FS_A + kb + fg * 8];
#pragma unroll
            for (int nt = 0; nt < 8; ++nt) {
                f16x8 bf = *(const f16x8*)&u.fg.sB[(nt * 16 + fr) * FS_A + kb + fg * 8];
                acc[nt] = __builtin_amdgcn_mfma_f32_16x16x32_f16(af, bf, acc[nt], 0, 0, 0);
            }
        }
#pragma unroll
        for (int nt = 0; nt < 8; ++nt) {
            int m = blk * 64 + wave * 16 + fg * 4;
            int n = nt * 16 + fr;
#pragma unroll
            for (int rr = 0; rr < 4; ++rr)
                pf[(size_t)(m + rr) * W + n] = (_Float16)acc[nt][rr];
        }
    } else {
        // ================= Wv role =================
        const int p0 = (blockIdx.x - PREP_FG_BLOCKS) * 8;
        if (tid < NANG) {
            float th = (float)tid * ((float)M_PI / (float)NANG);
            u.wv.cst[tid] = make_float2(cosf(th), sinf(th));
        }
        for (int i = tid; i < 8 * K_DIM; i += 256) u.wv.wrow[i] = 0.f;
        __syncthreads();
        const int px  = tid >> 5;
        const int sub = tid & 31;
        const int p = p0 + px;
        const float x = (float)(p & 127) - 63.5f;
        const float y = (float)(p >> 7) - 63.5f;
        float* prow = &u.wv.wrow[px * K_DIM];
        for (int a = sub; a < NANG; a += 32) {
            float2 c = u.wv.cst[a];
            float t = fmaf(x, c.x, fmaf(y, c.y, 63.5f));
            t = fminf(fmaxf(t, 0.f), 127.f);
            float tf = fminf(floorf(t), 126.f);
            int   ti = (int)tf;
            float wt = t - tf;
            float src = ((float)a + 0.5f) * 0.0625f - 0.5f;
            src = fminf(fmaxf(src, 0.f), 7.f);
            float vf = floorf(src);
            int   v0 = (int)vf;
            int   v1 = v0 + 1 < NV ? v0 + 1 : NV - 1;
            float wa = src - vf;
            float wA0 = (1.f - wa) * OUT_SCALE;
            atomicAdd(&prow[v0 * W + ti],     wA0 * (1.f - wt));
            atomicAdd(&prow[v0 * W + ti + 1], wA0 * wt);
            if (v1 != v0) {
                float wA1 = wa * OUT_SCALE;
                atomicAdd(&prow[v1 * W + ti],     wA1 * (1.f - wt));
                atomicAdd(&prow[v1 * W + ti + 1], wA1 * wt);
            }
        }
        __syncthreads();
        uint* wvu = (uint*)(wv + (size_t)p0 * K_DIM);
#pragma unroll
        for (int j = 0; j < 16; ++j) {
            int j2 = tid + 256 * j;
            float2 w2 = *(const float2*)&u.wv.wrow[j2 * 2];
            union { uint uu; struct { _Float16 lo, hi; } h; } pk;
            pk.h.lo = (_Float16)w2.x; pk.h.hi = (_Float16)w2.y;
            wvu[j2] = pk.uu;
        }
    }
}

// ---- kernel 2: persistent 2-tile 8-phase pipelined GEMM ----
// Out[m][n] = sum_k Pf[m][k] * Wv[n][k].  M=2048, N=16384, K=1024.
// 256 blocks (1/CU), each computes TWO n-adjacent 256x256 tiles (shared A
// panel) as one continuous 32-K-tile pipeline.  Tile-a's stores are spread
// 1/16-per-K-tile through tile-b's P4 phases (reg buffer `sto`, static
// switch(c) indexing); counted waits widened to vmcnt(12) = 8 stores +
// 4 lo-loads in flight.  XCD N-band swizzle: XCD x owns n-pairs [4x,4x+4).
#define NT2 32

__device__ __forceinline__ void fencebar() {
    asm volatile("" ::: "memory");
    __builtin_amdgcn_s_barrier();
    asm volatile("" ::: "memory");
}

__device__ __forceinline__ void stage_half(const _Float16* __restrict__ G, int R0,
                                           int h, int kt, _Float16* L, int tid) {
#pragma unroll
    for (int r = 0; r < 2; ++r) {
        const int c   = r * 512 + tid;            // chunk 0..1023 (16 B each)
        const int row = (h << 7) + (c >> 3);
        const int q   = c & 7;
        const _Float16* src = G + (size_t)(R0 + row) * K_DIM + kt * 64
                                + ((q ^ (row & 7)) << 3);
        _Float16* dst = L + (h << 13) + ((r * 512 + (tid & 448)) << 3); // wave-uniform
        glds16(src, dst);
    }
}

__device__ __forceinline__ f16x8 frag(const _Float16* L, int row, int q) {
    return *(const f16x8*)(L + row * 64 + ((q ^ (row & 7)) << 3));
}

__global__ __launch_bounds__(512, 2)
void k_gemm(const _Float16* __restrict__ A,
            const _Float16* __restrict__ Bm,
            float* __restrict__ out) {
    __shared__ _Float16 lds[65536];   // 128 KiB
    const int tid  = threadIdx.x;
    const int lane = tid & 63, wid = tid >> 6;
    const int wm = wid >> 2, wn = wid & 3;
    const int fr = lane & 15, fg = lane >> 4;

    // 256 blocks: XCD x (= flat&7) owns n-pairs [4x, 4x+4) across all 8 m-tiles.
    const int flat = blockIdx.x;
    const int xcd  = flat & 7;
    const int idx  = flat >> 3;            // 0..31
    const int m0   = (idx & 7) * 256;
    const int np   = xcd * 4 + (idx >> 3); // n-pair 0..31
    const int n0a  = np * 512;
    const int n0b  = n0a + 256;

    _Float16* const A0 = lds;
    _Float16* const B0 = lds + 16384;
    _Float16* const A1 = lds + 32768;
    _Float16* const B1 = lds + 49152;

    // prologue: tile0 (kt0, n0a) all 4 halves + tile1 lo halves
    stage_half(Bm, n0a, 0, 0, B0, tid);
    stage_half(A,  m0,  0, 0, A0, tid);
    stage_half(Bm, n0a, 1, 0, B0, tid);
    stage_half(A,  m0,  1, 0, A0, tid);
    stage_half(Bm, n0a, 0, 1, B1, tid);
    stage_half(A,  m0,  0, 1, A1, tid);
    asm volatile("s_waitcnt vmcnt(4)" ::: "memory");
    fencebar();

    f32x4 acc[8][4] = {};
    f32x4 sto[8][4] = {};
    f16x8 af[4][2], bf[4][2];
    const int ar = wm * 128 + fr;
    const int br = wn * 64 + fr;

    // per K-tile: 4 phases; stage slots P1->t+1 B-hi, P2->t+1 A-hi,
    // P3->t+2 B-lo, P4->t+2 A-lo.  c >= 0: store slice c of sto in P4.
    auto tile = [&](int t, _Float16* Ab, _Float16* Bb, _Float16* An, _Float16* Bn,
                    int nb1, int nb2, int c) __attribute__((always_inline)) {
        const int s1 = (t + 1 < NT2), s2 = (t + 2 < NT2);
        const int k1 = (t + 1) & 15, k2 = (t + 2) & 15;
        // ---- P1: read A m0-3 + B n0-1; MFMA m0-3 x n0-1 ----
#pragma unroll
        for (int i = 0; i < 4; ++i) {
            af[i][0] = frag(Ab, ar + i * 16, fg);
            af[i][1] = frag(Ab, ar + i * 16, 4 + fg);
        }
#pragma unroll
        for (int j = 0; j < 2; ++j) {
            bf[j][0] = frag(Bb, br + j * 16, fg);
            bf[j][1] = frag(Bb, br + j * 16, 4 + fg);
        }
        if (s1) stage_half(Bm, nb1, 1, k1, Bn, tid);
        fencebar();
        asm volatile("s_waitcnt lgkmcnt(0)" ::: "memory");
        __builtin_amdgcn_sched_barrier(0);
        __builtin_amdgcn_s_setprio(1);
#pragma unroll
        for (int i = 0; i < 4; ++i)
#pragma unroll
            for (int j = 0; j < 2; ++j) {
                acc[i][j] = __builtin_amdgcn_mfma_f32_16x16x32_f16(af[i][0], bf[j][0], acc[i][j], 0, 0, 0);
                acc[i][j] = __builtin_amdgcn_mfma_f32_16x16x32_f16(af[i][1], bf[j][1], acc[i][j], 0, 0, 0);
            }
        __builtin_amdgcn_s_setprio(0);
        fencebar();
        // ---- P2: read B n2-3; MFMA m0-3 x n2-3 ----
#pragma unroll
        for (int j = 2; j < 4; ++j) {
            bf[j][0] = frag(Bb, br + j * 16, fg);
            bf[j][1] = frag(Bb, br + j * 16, 4 + fg);
        }
        if (s1) stage_half(A, m0, 1, k1, An, tid);
        fencebar();
        asm volatile("s_waitcnt lgkmcnt(0)" ::: "memory");
        __builtin_amdgcn_sched_barrier(0);
        __builtin_amdgcn_s_setprio(1);
#pragma unroll
        for (int i = 0; i < 4; ++i)
#pragma unroll
            for (int j = 2; j < 4; ++j) {
                acc[i][j] = __builtin_amdgcn_mfma_f32_16x16x32_f16(af[i][0], bf[j][0], acc[i][j], 0, 0, 0);
                acc[i][j] = __builtin_amdgcn_mfma_f32_16x16x32_f16(af[i][1], bf[j][1], acc[i][j], 0, 0, 0);
            }
        __builtin_amdgcn_s_setprio(0);
        fencebar();
        // ---- P3: read A m4-7; MFMA m4-7 x n2-3 ----
#pragma unroll
        for (int i = 0; i < 4; ++i) {
            af[i][0] = frag(Ab, ar + 64 + i * 16, fg);
            af[i][1] = frag(Ab, ar + 64 + i * 16, 4 + fg);
        }
        if (s2) stage_half(Bm, nb2, 0, k2, Bb, tid);
        fencebar();
        asm volatile("s_waitcnt lgkmcnt(0)" ::: "memory");
        __builtin_amdgcn_sched_barrier(0);
        __builtin_amdgcn_s_setprio(1);
#pragma unroll
        for (int i = 0; i < 4; ++i)
#pragma unroll
            for (int j = 2; j < 4; ++j) {
                acc[4 + i][j] = __builtin_amdgcn_mfma_f32_16x16x32_f16(af[i][0], bf[j][0], acc[4 + i][j], 0, 0, 0);
                acc[4 + i][j] = __builtin_amdgcn_mfma_f32_16x16x32_f16(af[i][1], bf[j][1], acc[4 + i][j], 0, 0, 0);
            }
        __builtin_amdgcn_s_setprio(0);
        fencebar();
        // ---- P4: MFMA m4-7 x n0-1; spread stores; counted tile-end wait ----
        if (s2) stage_half(A, m0, 0, k2, Ab, tid);
        fencebar();
        __builtin_amdgcn_s_setprio(1);
#pragma unroll
        for (int i = 0; i < 4; ++i)
#pragma unroll
            for (int j = 0; j < 2; ++j) {
                acc[4 + i][j] = __builtin_amdgcn_mfma_f32_16x16x32_f16(af[i][0], bf[j][0], acc[4 + i][j], 0, 0, 0);
                acc[4 + i][j] = __builtin_amdgcn_mfma_f32_16x16x32_f16(af[i][1], bf[j][1], acc[4 + i][j], 0, 0, 0);
            }
        __builtin_amdgcn_s_setprio(0);
        if (c >= 0) {
            const int mS = m0 + wm * 128;
            const int nS = n0a + wn * 64;
#define STORE_PP(pp)  {                                                        \
            float* op = out + (size_t)(mS + ((pp) >> 2) * 16 + fg * 4) * NPIX  \
                            + nS + ((pp) & 3) * 16 + fr;                       \
            op[0]                = sto[(pp) >> 2][(pp) & 3][0];                \
            op[(size_t)NPIX]     = sto[(pp) >> 2][(pp) & 3][1];                \
            op[(size_t)2 * NPIX] = sto[(pp) >> 2][(pp) & 3][2];               \
            op[(size_t)3 * NPIX] = sto[(pp) >> 2][(pp) & 3][3]; }
            switch (c) {
            case 0:  STORE_PP(0)  STORE_PP(1)  break;
            case 1:  STORE_PP(2)  STORE_PP(3)  break;
            case 2:  STORE_PP(4)  STORE_PP(5)  break;
            case 3:  STORE_PP(6)  STORE_PP(7)  break;
            case 4:  STORE_PP(8)  STORE_PP(9)  break;
            case 5:  STORE_PP(10) STORE_PP(11) break;
            case 6:  STORE_PP(12) STORE_PP(13) break;
            case 7:  STORE_PP(14) STORE_PP(15) break;
            case 8:  STORE_PP(16) STORE_PP(17) break;
            case 9:  STORE_PP(18) STORE_PP(19) break;
            case 10: STORE_PP(20) STORE_PP(21) break;
            case 11: STORE_PP(22) STORE_PP(23) break;
            case 12: STORE_PP(24) STORE_PP(25) break;
            case 13: STORE_PP(26) STORE_PP(27) break;
            case 14: STORE_PP(28) STORE_PP(29) break;
            case 15: STORE_PP(30) STORE_PP(31) break;
            }
#undef STORE_PP
        }
        if (s2) {
            if (c >= 0) asm volatile("s_waitcnt vmcnt(12)" ::: "memory");
            else        asm volatile("s_waitcnt vmcnt(4)"  ::: "memory");
        } else if (s1) {
            if (c >= 0) asm volatile("s_waitcnt vmcnt(8)" ::: "memory");
            else        asm volatile("s_waitcnt vmcnt(0)" ::: "memory");
        }
        fencebar();
    };

    // tile-a: K-tiles 0..15 (output @ n0a)
    for (int tt = 0; tt < 16; tt += 2) {
        const int u1 = tt + 1, u2 = tt + 2, u3 = tt + 3;
        tile(tt,     A0, B0, A1, B1, (u1 < 16) ? n0a : n0b, (u2 < 16) ? n0a : n0b, -1);
        tile(tt + 1, A1, B1, A0, B0, (u2 < 16) ? n0a : n0b, (u3 < 16) ? n0a : n0b, -1);
    }
    // boundary: snapshot tile-a result, reset accumulator
#pragma unroll
    for (int i = 0; i < 8; ++i)
#pragma unroll
        for (int j = 0; j < 4; ++j) {
            sto[i][j] = acc[i][j];
            acc[i][j] = (f32x4){0.f, 0.f, 0.f, 0.f};
        }
    // tile-b: K-tiles 16..31 (output @ n0b), tile-a stores spread via c
    for (int tt = 16; tt < 32; tt += 2) {
        tile(tt,     A0, B0, A1, B1, n0b, n0b, tt - 16);
        tile(tt + 1, A1, B1, A0, B0, n0b, n0b, tt - 15);
    }

    // final epilogue: tile-b acc -> out @ n0b
#pragma unroll
    for (int i = 0; i < 8; ++i) {
#pragma unroll
        for (int j = 0; j < 4; ++j) {
            const int m = m0 + wm * 128 + i * 16 + fg * 4;
            const int n = n0b + wn * 64 + j * 16 + fr;
            float* op = out + (size_t)m * NPIX + n;
#pragma unroll
            for (int rr = 0; rr < 4; ++rr)
                op[(size_t)rr * NPIX] = acc[i][j][rr];
        }
    }
}

extern "C" void kernel_launch(void* const* d_in, const int* in_sizes, int n_in,
                              void* d_out, int out_size, void* d_ws, size_t ws_size,
                              hipStream_t stream) {
    _Float16*   pf = (_Float16*)((char*)d_ws + PF_OFF);
    _Float16*   wv = (_Float16*)((char*)d_ws + WV_OFF);

    Ptrs8 in;
    for (int i = 0; i < NV; ++i) in.p[i] = (const float*)d_in[i];

    k_prep<<<PREP_FG_BLOCKS + NPIX / 8, 256, 0, stream>>>(in, pf, wv);
    k_gemm<<<256, 512, 0, stream>>>(pf, wv, (float*)d_out);
}

// Round 4
// 260.140 us; speedup vs baseline: 2.2053x; 2.2053x over previous
//
#include <hip/hip_runtime.h>
#include <math.h>

#define W 128
#define NANG 128
#define SZ 128
#define NV 8
#define NROWS 2048          // B*C*H
#define K_DIM 1024          // NV * W
#define NPIX 16384          // SZ * SZ
#define OUT_SCALE 0.012271846303085130f   // pi / 256

typedef _Float16 f16x8 __attribute__((ext_vector_type(8)));
typedef _Float16 f16x4 __attribute__((ext_vector_type(4)));
typedef float    f32x4 __attribute__((ext_vector_type(4)));

// ws layout:
//   [36864, +4MiB)  : Pf  f16 [2048 r][8 v][128 t]
//   [.., +32MiB)    : Wv  f16 [16384 pix][1024 k]
#define PF_OFF 36864
#define WV_OFF (36864 + (size_t)NROWS * K_DIM * 2)

struct Ptrs8 { const float* p[8]; };

__device__ __forceinline__ void glds16(const void* g, void* l) {
    __builtin_amdgcn_global_load_lds(
        (const __attribute__((address_space(1))) void*)g,
        (__attribute__((address_space(3))) void*)l, 16, 0, 0);
}

// ---- kernel 1: fused prep ----
// blocks [0,256): filter-GEMM  Pf[(r,v)][t] = sum_s In[v][r][s] * C[t][s]
//   with the circulant C built in LDS from locally-computed filter taps.
// blocks [256,2304): Wv[pixel][k] fused angle-lerp x detector-lerp weights,
//   with the cos/sin table computed locally.
#define FS_A 136   // padded LDS row stride (halfs): +8 -> 2-way bank alias only
#define PREP_FG_BLOCKS 256

union PrepLds {
    struct {                        // fgemm role (52.7 KB)
        _Float16 sA[64 * FS_A];
        _Float16 sB[128 * FS_A];
        float    kl[W];
    } fg;
    struct {                        // wv role (33.8 KB)
        float  wrow[8 * K_DIM];
        float2 cst[NANG];
    } wv;
};

__global__ __launch_bounds__(256)
void k_prep(Ptrs8 in, _Float16* __restrict__ pf, _Float16* __restrict__ wv) {
    __shared__ PrepLds u;
    const int tid = threadIdx.x;

    if (blockIdx.x < PREP_FG_BLOCKS) {
        // ================= filter-GEMM role =================
        const int blk  = blockIdx.x;
        const int lane = tid & 63, wave = tid >> 6;
        const int fr = lane & 15, fg = lane >> 4;

        if (tid < W) {
            const int d = tid;
            const float w0 = 6.283185307179586f / (float)W * (float)d;
            float s = 0.f;
            for (int f = 1; f < 64; ++f)
                s = fmaf((float)f, __cosf(w0 * (float)f), s);
            s = 2.f * s + 64.f * ((d & 1) ? -1.f : 1.f);
            u.fg.kl[d] = s * (1.f / (float)(W * W));
        }
        {
            const int i   = tid >> 5;          // row-within-view-group 0..7
            const int pos = (tid & 31) * 4;    // f32 position 0..124
#pragma unroll
            for (int v = 0; v < NV; ++v) {
                float4 x = *(const float4*)(in.p[v] + (size_t)(blk * 8 + i) * W + pos);
                f16x4 h = { (_Float16)x.x, (_Float16)x.y, (_Float16)x.z, (_Float16)x.w };
                *(f16x4*)&u.fg.sA[(i * 8 + v) * FS_A + pos] = h;
            }
        }
        __syncthreads();
        for (int e = tid; e < W * W; e += 256) {
            const int t = e >> 7, s = e & 127;
            u.fg.sB[t * FS_A + s] = (_Float16)u.fg.kl[(t - s) & (W - 1)];
        }
        __syncthreads();

        f32x4 acc[8] = {};
#pragma unroll
        for (int kb = 0; kb < W; kb += 32) {
            f16x8 af = *(const f16x8*)&u.fg.sA[(wave * 16 + fr) * FS_A + kb + fg * 8];
#pragma unroll
            for (int nt = 0; nt < 8; ++nt) {
                f16x8 bf = *(const f16x8*)&u.fg.sB[(nt * 16 + fr) * FS_A + kb + fg * 8];
                acc[nt] = __builtin_amdgcn_mfma_f32_16x16x32_f16(af, bf, acc[nt], 0, 0, 0);
            }
        }
#pragma unroll
        for (int nt = 0; nt < 8; ++nt) {
            int m = blk * 64 + wave * 16 + fg * 4;
            int n = nt * 16 + fr;
#pragma unroll
            for (int rr = 0; rr < 4; ++rr)
                pf[(size_t)(m + rr) * W + n] = (_Float16)acc[nt][rr];
        }
    } else {
        // ================= Wv role =================
        const int p0 = (blockIdx.x - PREP_FG_BLOCKS) * 8;
        if (tid < NANG) {
            float th = (float)tid * ((float)M_PI / (float)NANG);
            u.wv.cst[tid] = make_float2(cosf(th), sinf(th));
        }
        for (int i = tid; i < 8 * K_DIM; i += 256) u.wv.wrow[i] = 0.f;
        __syncthreads();
        const int px  = tid >> 5;
        const int sub = tid & 31;
        const int p = p0 + px;
        const float x = (float)(p & 127) - 63.5f;
        const float y = (float)(p >> 7) - 63.5f;
        float* prow = &u.wv.wrow[px * K_DIM];
        for (int a = sub; a < NANG; a += 32) {
            float2 c = u.wv.cst[a];
            float t = fmaf(x, c.x, fmaf(y, c.y, 63.5f));
            t = fminf(fmaxf(t, 0.f), 127.f);
            float tf = fminf(floorf(t), 126.f);
            int   ti = (int)tf;
            float wt = t - tf;
            float src = ((float)a + 0.5f) * 0.0625f - 0.5f;
            src = fminf(fmaxf(src, 0.f), 7.f);
            float vf = floorf(src);
            int   v0 = (int)vf;
            int   v1 = v0 + 1 < NV ? v0 + 1 : NV - 1;
            float wa = src - vf;
            float wA0 = (1.f - wa) * OUT_SCALE;
            atomicAdd(&prow[v0 * W + ti],     wA0 * (1.f - wt));
            atomicAdd(&prow[v0 * W + ti + 1], wA0 * wt);
            if (v1 != v0) {
                float wA1 = wa * OUT_SCALE;
                atomicAdd(&prow[v1 * W + ti],     wA1 * (1.f - wt));
                atomicAdd(&prow[v1 * W + ti + 1], wA1 * wt);
            }
        }
        __syncthreads();
        uint* wvu = (uint*)(wv + (size_t)p0 * K_DIM);
#pragma unroll
        for (int j = 0; j < 16; ++j) {
            int j2 = tid + 256 * j;
            float2 w2 = *(const float2*)&u.wv.wrow[j2 * 2];
            union { uint uu; struct { _Float16 lo, hi; } h; } pk;
            pk.h.lo = (_Float16)w2.x; pk.h.hi = (_Float16)w2.y;
            wvu[j2] = pk.uu;
        }
    }
}

// ---- kernel 2: 256x256-tile 8-phase pipelined GEMM (unpinned phases) ----
// Out[m][n] = sum_k Pf[m][k] * Wv[n][k].  M=2048, N=16384, K=1024.
// 512 threads = 8 waves (2M x 4N), per-wave 128x64 output, BK=64, NT=16.
// LDS 128 KiB: 2 buffers x (A 32K | B 32K).  XOR swizzle q ^= row&7 both-sides.
// Change vs r2: per-phase ds_reads are NOT pinned behind the barrier with
// lgkmcnt(0)+sched_barrier(0); compiler emits counted lgkmcnt and interleaves
// reads with MFMAs (in-phase LDS/MFMA pipe overlap).  Race safety: every read
// has a same-phase consumer + an explicit phase-end lgkmcnt(0) drain (free,
// runs while waiting at the barrier) before any re-stage of that buffer.
#define NT 16

__device__ __forceinline__ void fencebar() {
    asm volatile("" ::: "memory");
    __builtin_amdgcn_s_barrier();
    asm volatile("" ::: "memory");
}

__device__ __forceinline__ void stage_half(const _Float16* __restrict__ G, int R0,
                                           int h, int kt, _Float16* L, int tid) {
#pragma unroll
    for (int r = 0; r < 2; ++r) {
        const int c   = r * 512 + tid;            // chunk 0..1023 (16 B each)
        const int row = (h << 7) + (c >> 3);
        const int q   = c & 7;
        const _Float16* src = G + (size_t)(R0 + row) * K_DIM + kt * 64
                                + ((q ^ (row & 7)) << 3);
        _Float16* dst = L + (h << 13) + ((r * 512 + (tid & 448)) << 3); // wave-uniform
        glds16(src, dst);
    }
}

__device__ __forceinline__ f16x8 frag(const _Float16* L, int row, int q) {
    return *(const f16x8*)(L + row * 64 + ((q ^ (row & 7)) << 3));
}

__global__ __launch_bounds__(512, 2)
void k_gemm(const _Float16* __restrict__ A,
            const _Float16* __restrict__ Bm,
            float* __restrict__ out) {
    __shared__ _Float16 lds[65536];   // 128 KiB
    const int tid  = threadIdx.x;
    const int lane = tid & 63, wid = tid >> 6;
    const int wm = wid >> 2, wn = wid & 3;
    const int fr = lane & 15, fg = lane >> 4;

    // bijective XCD swizzle (512 blocks % 8 == 0): XCD x owns n-tiles
    // [x*8, x*8+8) across all 8 m-tiles.
    const int flat = blockIdx.y * 64 + blockIdx.x;
    const int x    = flat & 7;         // XCD id (dispatch round-robin)
    const int idx  = flat >> 3;        // 0..63 within XCD
    const int m0 = (idx >> 3) * 256;
    const int n0 = (x * 8 + (idx & 7)) * 256;

    _Float16* const A0 = lds;
    _Float16* const B0 = lds + 16384;
    _Float16* const A1 = lds + 32768;
    _Float16* const B1 = lds + 49152;

    // prologue: tile0 all 4 halves + tile1 B-lo, A-lo  (12 loads/thread)
    stage_half(Bm, n0, 0, 0, B0, tid);
    stage_half(A,  m0, 0, 0, A0, tid);
    stage_half(Bm, n0, 1, 0, B0, tid);
    stage_half(A,  m0, 1, 0, A0, tid);
    stage_half(Bm, n0, 0, 1, B1, tid);
    stage_half(A,  m0, 0, 1, A1, tid);
    asm volatile("s_waitcnt vmcnt(4)" ::: "memory");  // tile0 landed; tile1 lo in flight
    fencebar();

    f32x4 acc[8][4] = {};
    f16x8 af[4][2], bf[4][2];
    const int ar = wm * 128 + fr;
    const int br = wn * 64 + fr;

    // per K-tile: 4 phases.  Stage slots (issue at phase start; buffer's last
    // LDS reader drained at the prior phase-end lgkmcnt+barrier):
    // P1->t+1 B-hi (other buf), P2->t+1 A-hi (other buf),
    // P3->t+2 B-lo (this buf; B reads done P2), P4->t+2 A-lo (A reads done P3).
    auto tile = [&](int t, _Float16* Ab, _Float16* Bb, _Float16* An, _Float16* Bn)
        __attribute__((always_inline)) {
        // ---- P1: stage; read A m0-3 + B n0-1; MFMA m0-3 x n0-1 ----
        if (t + 1 < NT) stage_half(Bm, n0, 1, t + 1, Bn, tid);
#pragma unroll
        for (int i = 0; i < 4; ++i) {
            af[i][0] = frag(Ab, ar + i * 16, fg);
            af[i][1] = frag(Ab, ar + i * 16, 4 + fg);
        }
#pragma unroll
        for (int j = 0; j < 2; ++j) {
            bf[j][0] = frag(Bb, br + j * 16, fg);
            bf[j][1] = frag(Bb, br + j * 16, 4 + fg);
        }
        fencebar();
        __builtin_amdgcn_s_setprio(1);
#pragma unroll
        for (int i = 0; i < 4; ++i)
#pragma unroll
            for (int j = 0; j < 2; ++j) {
                acc[i][j] = __builtin_amdgcn_mfma_f32_16x16x32_f16(af[i][0], bf[j][0], acc[i][j], 0, 0, 0);
                acc[i][j] = __builtin_amdgcn_mfma_f32_16x16x32_f16(af[i][1], bf[j][1], acc[i][j], 0, 0, 0);
            }
        __builtin_amdgcn_s_setprio(0);
        asm volatile("s_waitcnt lgkmcnt(0)" ::: "memory");   // phase-end drain (free)
        fencebar();
        // ---- P2: stage; read B n2-3; MFMA m0-3 x n2-3 ----
        if (t + 1 < NT) stage_half(A, m0, 1, t + 1, An, tid);
#pragma unroll
        for (int j = 2; j < 4; ++j) {
            bf[j][0] = frag(Bb, br + j * 16, fg);
            bf[j][1] = frag(Bb, br + j * 16, 4 + fg);
        }
        fencebar();
        __builtin_amdgcn_s_setprio(1);
#pragma unroll
        for (int i = 0; i < 4; ++i)
#pragma unroll
            for (int j = 2; j < 4; ++j) {
                acc[i][j] = __builtin_amdgcn_mfma_f32_16x16x32_f16(af[i][0], bf[j][0], acc[i][j], 0, 0, 0);
                acc[i][j] = __builtin_amdgcn_mfma_f32_16x16x32_f16(af[i][1], bf[j][1], acc[i][j], 0, 0, 0);
            }
        __builtin_amdgcn_s_setprio(0);
        asm volatile("s_waitcnt lgkmcnt(0)" ::: "memory");   // B reads drained
        fencebar();
        // ---- P3: stage B-lo t+2 into Bb; read A m4-7; MFMA m4-7 x n2-3 ----
        if (t + 2 < NT) stage_half(Bm, n0, 0, t + 2, Bb, tid);
#pragma unroll
        for (int i = 0; i < 4; ++i) {
            af[i][0] = frag(Ab, ar + 64 + i * 16, fg);
            af[i][1] = frag(Ab, ar + 64 + i * 16, 4 + fg);
        }
        fencebar();
        __builtin_amdgcn_s_setprio(1);
#pragma unroll
        for (int i = 0; i < 4; ++i)
#pragma unroll
            for (int j = 2; j < 4; ++j) {
                acc[4 + i][j] = __builtin_amdgcn_mfma_f32_16x16x32_f16(af[i][0], bf[j][0], acc[4 + i][j], 0, 0, 0);
                acc[4 + i][j] = __builtin_amdgcn_mfma_f32_16x16x32_f16(af[i][1], bf[j][1], acc[4 + i][j], 0, 0, 0);
            }
        __builtin_amdgcn_s_setprio(0);
        asm volatile("s_waitcnt lgkmcnt(0)" ::: "memory");   // A reads drained
        fencebar();
        // ---- P4: stage A-lo t+2 into Ab; MFMA m4-7 x n0-1; counted tile-end wait ----
        if (t + 2 < NT) stage_half(A, m0, 0, t + 2, Ab, tid);
        fencebar();
        __builtin_amdgcn_s_setprio(1);
#pragma unroll
        for (int i = 0; i < 4; ++i)
#pragma unroll
            for (int j = 0; j < 2; ++j) {
                acc[4 + i][j] = __builtin_amdgcn_mfma_f32_16x16x32_f16(af[i][0], bf[j][0], acc[4 + i][j], 0, 0, 0);
                acc[4 + i][j] = __builtin_amdgcn_mfma_f32_16x16x32_f16(af[i][1], bf[j][1], acc[4 + i][j], 0, 0, 0);
            }
        __builtin_amdgcn_s_setprio(0);
        if (t + 2 < NT)      asm volatile("s_waitcnt vmcnt(4)" ::: "memory");
        else if (t + 1 < NT) asm volatile("s_waitcnt vmcnt(0)" ::: "memory");
        fencebar();
    };

    for (int tt = 0; tt < NT; tt += 2) {
        tile(tt,     A0, B0, A1, B1);
        tile(tt + 1, A1, B1, A0, B0);
    }

    // epilogue: C/D col = fr (n), row = fg*4 + rr (m within 16)
#pragma unroll
    for (int i = 0; i < 8; ++i) {
#pragma unroll
        for (int j = 0; j < 4; ++j) {
            const int m = m0 + wm * 128 + i * 16 + fg * 4;
            const int n = n0 + wn * 64 + j * 16 + fr;
            float* op = out + (size_t)m * NPIX + n;
#pragma unroll
            for (int rr = 0; rr < 4; ++rr)
                op[(size_t)rr * NPIX] = acc[i][j][rr];
        }
    }
}

extern "C" void kernel_launch(void* const* d_in, const int* in_sizes, int n_in,
                              void* d_out, int out_size, void* d_ws, size_t ws_size,
                              hipStream_t stream) {
    _Float16*   pf = (_Float16*)((char*)d_ws + PF_OFF);
    _Float16*   wv = (_Float16*)((char*)d_ws + WV_OFF);

    Ptrs8 in;
    for (int i = 0; i < NV; ++i) in.p[i] = (const float*)d_in[i];

    k_prep<<<PREP_FG_BLOCKS + NPIX / 8, 256, 0, stream>>>(in, pf, wv);
    dim3 grid(NPIX / 256, NROWS / 256);   // 64 x 8 = 512 blocks
    k_gemm<<<grid, 512, 0, stream>>>(pf, wv, (float*)d_out);
}

// Round 5
// 258.000 us; speedup vs baseline: 2.2236x; 1.0083x over previous
//
#include <hip/hip_runtime.h>
#include <math.h>

#define W 128
#define NANG 128
#define SZ 128
#define NV 8
#define NROWS 2048          // B*C*H
#define K_DIM 1024          // NV * W
#define NPIX 16384          // SZ * SZ
#define OUT_SCALE 0.012271846303085130f   // pi / 256

typedef _Float16 f16x8 __attribute__((ext_vector_type(8)));
typedef _Float16 f16x4 __attribute__((ext_vector_type(4)));
typedef float    f32x4 __attribute__((ext_vector_type(4)));

// ws layout:
//   [36864, +4MiB)  : Pf  f16 [2048 r][8 v][128 t]
//   [.., +32MiB)    : Wv  f16 [16384 pix][1024 k]
#define PF_OFF 36864
#define WV_OFF (36864 + (size_t)NROWS * K_DIM * 2)

struct Ptrs8 { const float* p[8]; };

__device__ __forceinline__ void glds16(const void* g, void* l) {
    __builtin_amdgcn_global_load_lds(
        (const __attribute__((address_space(1))) void*)g,
        (__attribute__((address_space(3))) void*)l, 16, 0, 0);
}

// ---- kernel 1: fused prep ----
// blocks [0,256): filter-GEMM  Pf[(r,v)][t] = sum_s In[v][r][s] * C[t][s]
//   with the circulant C built in LDS from locally-computed filter taps.
// blocks [256,2304): Wv[pixel][k] fused angle-lerp x detector-lerp weights,
//   with the cos/sin table computed locally.
#define FS_A 136   // padded LDS row stride (halfs): +8 -> 2-way bank alias only
#define PREP_FG_BLOCKS 256

union PrepLds {
    struct {                        // fgemm role (52.7 KB)
        _Float16 sA[64 * FS_A];
        _Float16 sB[128 * FS_A];
        float    kl[W];
    } fg;
    struct {                        // wv role (33.8 KB)
        float  wrow[8 * K_DIM];
        float2 cst[NANG];
    } wv;
};

__global__ __launch_bounds__(256)
void k_prep(Ptrs8 in, _Float16* __restrict__ pf, _Float16* __restrict__ wv) {
    __shared__ PrepLds u;
    const int tid = threadIdx.x;

    if (blockIdx.x < PREP_FG_BLOCKS) {
        // ================= filter-GEMM role =================
        const int blk  = blockIdx.x;
        const int lane = tid & 63, wave = tid >> 6;
        const int fr = lane & 15, fg = lane >> 4;

        if (tid < W) {
            const int d = tid;
            const float w0 = 6.283185307179586f / (float)W * (float)d;
            float s = 0.f;
            for (int f = 1; f < 64; ++f)
                s = fmaf((float)f, __cosf(w0 * (float)f), s);
            s = 2.f * s + 64.f * ((d & 1) ? -1.f : 1.f);
            u.fg.kl[d] = s * (1.f / (float)(W * W));
        }
        {
            const int i   = tid >> 5;          // row-within-view-group 0..7
            const int pos = (tid & 31) * 4;    // f32 position 0..124
#pragma unroll
            for (int v = 0; v < NV; ++v) {
                float4 x = *(const float4*)(in.p[v] + (size_t)(blk * 8 + i) * W + pos);
                f16x4 h = { (_Float16)x.x, (_Float16)x.y, (_Float16)x.z, (_Float16)x.w };
                *(f16x4*)&u.fg.sA[(i * 8 + v) * FS_A + pos] = h;
            }
        }
        __syncthreads();
        for (int e = tid; e < W * W; e += 256) {
            const int t = e >> 7, s = e & 127;
            u.fg.sB[t * FS_A + s] = (_Float16)u.fg.kl[(t - s) & (W - 1)];
        }
        __syncthreads();

        f32x4 acc[8] = {};
#pragma unroll
        for (int kb = 0; kb < W; kb += 32) {
            f16x8 af = *(const f16x8*)&u.fg.sA[(wave * 16 + fr) * FS_A + kb + fg * 8];
#pragma unroll
            for (int nt = 0; nt < 8; ++nt) {
                f16x8 bf = *(const f16x8*)&u.fg.sB[(nt * 16 + fr) * FS_A + kb + fg * 8];
                acc[nt] = __builtin_amdgcn_mfma_f32_16x16x32_f16(af, bf, acc[nt], 0, 0, 0);
            }
        }
#pragma unroll
        for (int nt = 0; nt < 8; ++nt) {
            int m = blk * 64 + wave * 16 + fg * 4;
            int n = nt * 16 + fr;
#pragma unroll
            for (int rr = 0; rr < 4; ++rr)
                pf[(size_t)(m + rr) * W + n] = (_Float16)acc[nt][rr];
        }
    } else {
        // ================= Wv role =================
        const int p0 = (blockIdx.x - PREP_FG_BLOCKS) * 8;
        if (tid < NANG) {
            float th = (float)tid * ((float)M_PI / (float)NANG);
            u.wv.cst[tid] = make_float2(cosf(th), sinf(th));
        }
        for (int i = tid; i < 8 * K_DIM; i += 256) u.wv.wrow[i] = 0.f;
        __syncthreads();
        const int px  = tid >> 5;
        const int sub = tid & 31;
        const int p = p0 + px;
        const float x = (float)(p & 127) - 63.5f;
        const float y = (float)(p >> 7) - 63.5f;
        float* prow = &u.wv.wrow[px * K_DIM];
        for (int a = sub; a < NANG; a += 32) {
            float2 c = u.wv.cst[a];
            float t = fmaf(x, c.x, fmaf(y, c.y, 63.5f));
            t = fminf(fmaxf(t, 0.f), 127.f);
            float tf = fminf(floorf(t), 126.f);
            int   ti = (int)tf;
            float wt = t - tf;
            float src = ((float)a + 0.5f) * 0.0625f - 0.5f;
            src = fminf(fmaxf(src, 0.f), 7.f);
            float vf = floorf(src);
            int   v0 = (int)vf;
            int   v1 = v0 + 1 < NV ? v0 + 1 : NV - 1;
            float wa = src - vf;
            float wA0 = (1.f - wa) * OUT_SCALE;
            atomicAdd(&prow[v0 * W + ti],     wA0 * (1.f - wt));
            atomicAdd(&prow[v0 * W + ti + 1], wA0 * wt);
            if (v1 != v0) {
                float wA1 = wa * OUT_SCALE;
                atomicAdd(&prow[v1 * W + ti],     wA1 * (1.f - wt));
                atomicAdd(&prow[v1 * W + ti + 1], wA1 * wt);
            }
        }
        __syncthreads();
        uint* wvu = (uint*)(wv + (size_t)p0 * K_DIM);
#pragma unroll
        for (int j = 0; j < 16; ++j) {
            int j2 = tid + 256 * j;
            float2 w2 = *(const float2*)&u.wv.wrow[j2 * 2];
            union { uint uu; struct { _Float16 lo, hi; } h; } pk;
            pk.h.lo = (_Float16)w2.x; pk.h.hi = (_Float16)w2.y;
            wvu[j2] = pk.uu;
        }
    }
}

// ---- kernel 2: 256x256-tile pipelined GEMM, ONE barrier per phase ----
// Out[m][n] = sum_k Pf[m][k] * Wv[n][k].  M=2048, N=16384, K=1024.
// 512 threads = 8 waves (2M x 4N), per-wave 128x64 output, BK=64, NT=16.
// LDS 128 KiB: 2 buffers x (A 32K | B 32K).  XOR swizzle q ^= row&7 both-sides.
// Change vs r4: the pre-MFMA barrier is REMOVED.  Phase = {stage issue;
// ds_reads; MFMA (compiler-counted lgkm waits); lgkmcnt(0); barrier}.
// One sync point per phase lets a wave that finishes MFMA early run the next
// phase's read window while other waves are still on the matrix pipe
// (cross-wave LDS/MFMA overlap).  Race safety: each stage slot's target
// region had its last reader drained by a PREVIOUS phase's lgkmcnt(0)+barrier
// (B-lo read P1-P2 -> restaged P3; A-lo read P1-P3 -> restaged P4; other-buf
// halves read last tile).  glds->ds_read hazards guarded by the unchanged
// tile-end counted vmcnt (in-order retire: oldest 8 = next tile's 4 halves).
#define NT 16

__device__ __forceinline__ void fencebar() {
    asm volatile("" ::: "memory");
    __builtin_amdgcn_s_barrier();
    asm volatile("" ::: "memory");
}

__device__ __forceinline__ void stage_half(const _Float16* __restrict__ G, int R0,
                                           int h, int kt, _Float16* L, int tid) {
#pragma unroll
    for (int r = 0; r < 2; ++r) {
        const int c   = r * 512 + tid;            // chunk 0..1023 (16 B each)
        const int row = (h << 7) + (c >> 3);
        const int q   = c & 7;
        const _Float16* src = G + (size_t)(R0 + row) * K_DIM + kt * 64
                                + ((q ^ (row & 7)) << 3);
        _Float16* dst = L + (h << 13) + ((r * 512 + (tid & 448)) << 3); // wave-uniform
        glds16(src, dst);
    }
}

__device__ __forceinline__ f16x8 frag(const _Float16* L, int row, int q) {
    return *(const f16x8*)(L + row * 64 + ((q ^ (row & 7)) << 3));
}

__global__ __launch_bounds__(512, 2)
void k_gemm(const _Float16* __restrict__ A,
            const _Float16* __restrict__ Bm,
            float* __restrict__ out) {
    __shared__ _Float16 lds[65536];   // 128 KiB
    const int tid  = threadIdx.x;
    const int lane = tid & 63, wid = tid >> 6;
    const int wm = wid >> 2, wn = wid & 3;
    const int fr = lane & 15, fg = lane >> 4;

    // bijective XCD swizzle (512 blocks % 8 == 0): XCD x owns n-tiles
    // [x*8, x*8+8) across all 8 m-tiles.
    const int flat = blockIdx.y * 64 + blockIdx.x;
    const int x    = flat & 7;         // XCD id (dispatch round-robin)
    const int idx  = flat >> 3;        // 0..63 within XCD
    const int m0 = (idx >> 3) * 256;
    const int n0 = (x * 8 + (idx & 7)) * 256;

    _Float16* const A0 = lds;
    _Float16* const B0 = lds + 16384;
    _Float16* const A1 = lds + 32768;
    _Float16* const B1 = lds + 49152;

    // prologue: tile0 all 4 halves + tile1 B-lo, A-lo  (12 loads/thread)
    stage_half(Bm, n0, 0, 0, B0, tid);
    stage_half(A,  m0, 0, 0, A0, tid);
    stage_half(Bm, n0, 1, 0, B0, tid);
    stage_half(A,  m0, 1, 0, A0, tid);
    stage_half(Bm, n0, 0, 1, B1, tid);
    stage_half(A,  m0, 0, 1, A1, tid);
    asm volatile("s_waitcnt vmcnt(4)" ::: "memory");  // tile0 landed; tile1 lo in flight
    fencebar();

    f32x4 acc[8][4] = {};
    f16x8 af[4][2], bf[4][2];
    const int ar = wm * 128 + fr;
    const int br = wn * 64 + fr;

    // per K-tile: 4 single-barrier phases.  Stage slots:
    // P1->t+1 B-hi (other buf), P2->t+1 A-hi (other buf),
    // P3->t+2 B-lo (cur buf; B reads done by P2 end),
    // P4->t+2 A-lo (cur buf; A reads done by P3 end).
    auto tile = [&](int t, _Float16* Ab, _Float16* Bb, _Float16* An, _Float16* Bn)
        __attribute__((always_inline)) {
        // ---- P1: stage; read A m0-3 + B n0-1; MFMA m0-3 x n0-1 ----
        if (t + 1 < NT) stage_half(Bm, n0, 1, t + 1, Bn, tid);
#pragma unroll
        for (int i = 0; i < 4; ++i) {
            af[i][0] = frag(Ab, ar + i * 16, fg);
            af[i][1] = frag(Ab, ar + i * 16, 4 + fg);
        }
#pragma unroll
        for (int j = 0; j < 2; ++j) {
            bf[j][0] = frag(Bb, br + j * 16, fg);
            bf[j][1] = frag(Bb, br + j * 16, 4 + fg);
        }
        __builtin_amdgcn_s_setprio(1);
#pragma unroll
        for (int i = 0; i < 4; ++i)
#pragma unroll
            for (int j = 0; j < 2; ++j) {
                acc[i][j] = __builtin_amdgcn_mfma_f32_16x16x32_f16(af[i][0], bf[j][0], acc[i][j], 0, 0, 0);
                acc[i][j] = __builtin_amdgcn_mfma_f32_16x16x32_f16(af[i][1], bf[j][1], acc[i][j], 0, 0, 0);
            }
        __builtin_amdgcn_s_setprio(0);
        asm volatile("s_waitcnt lgkmcnt(0)" ::: "memory");   // phase-end drain
        fencebar();
        // ---- P2: stage; read B n2-3; MFMA m0-3 x n2-3 ----
        if (t + 1 < NT) stage_half(A, m0, 1, t + 1, An, tid);
#pragma unroll
        for (int j = 2; j < 4; ++j) {
            bf[j][0] = frag(Bb, br + j * 16, fg);
            bf[j][1] = frag(Bb, br + j * 16, 4 + fg);
        }
        __builtin_amdgcn_s_setprio(1);
#pragma unroll
        for (int i = 0; i < 4; ++i)
#pragma unroll
            for (int j = 2; j < 4; ++j) {
                acc[i][j] = __builtin_amdgcn_mfma_f32_16x16x32_f16(af[i][0], bf[j][0], acc[i][j], 0, 0, 0);
                acc[i][j] = __builtin_amdgcn_mfma_f32_16x16x32_f16(af[i][1], bf[j][1], acc[i][j], 0, 0, 0);
            }
        __builtin_amdgcn_s_setprio(0);
        asm volatile("s_waitcnt lgkmcnt(0)" ::: "memory");   // all B reads drained
        fencebar();
        // ---- P3: stage B-lo t+2 into Bb; read A m4-7; MFMA m4-7 x n2-3 ----
        if (t + 2 < NT) stage_half(Bm, n0, 0, t + 2, Bb, tid);
#pragma unroll
        for (int i = 0; i < 4; ++i) {
            af[i][0] = frag(Ab, ar + 64 + i * 16, fg);
            af[i][1] = frag(Ab, ar + 64 + i * 16, 4 + fg);
        }
        __builtin_amdgcn_s_setprio(1);
#pragma unroll
        for (int i = 0; i < 4; ++i)
#pragma unroll
            for (int j = 2; j < 4; ++j) {
                acc[4 + i][j] = __builtin_amdgcn_mfma_f32_16x16x32_f16(af[i][0], bf[j][0], acc[4 + i][j], 0, 0, 0);
                acc[4 + i][j] = __builtin_amdgcn_mfma_f32_16x16x32_f16(af[i][1], bf[j][1], acc[4 + i][j], 0, 0, 0);
            }
        __builtin_amdgcn_s_setprio(0);
        asm volatile("s_waitcnt lgkmcnt(0)" ::: "memory");   // all A reads drained
        fencebar();
        // ---- P4: stage A-lo t+2 into Ab; MFMA m4-7 x n0-1; counted tile-end wait ----
        if (t + 2 < NT) stage_half(A, m0, 0, t + 2, Ab, tid);
        __builtin_amdgcn_s_setprio(1);
#pragma unroll
        for (int i = 0; i < 4; ++i)
#pragma unroll
            for (int j = 0; j < 2; ++j) {
                acc[4 + i][j] = __builtin_amdgcn_mfma_f32_16x16x32_f16(af[i][0], bf[j][0], acc[4 + i][j], 0, 0, 0);
                acc[4 + i][j] = __builtin_amdgcn_mfma_f32_16x16x32_f16(af[i][1], bf[j][1], acc[4 + i][j], 0, 0, 0);
            }
        __builtin_amdgcn_s_setprio(0);
        if (t + 2 < NT)      asm volatile("s_waitcnt vmcnt(4)" ::: "memory");
        else if (t + 1 < NT) asm volatile("s_waitcnt vmcnt(0)" ::: "memory");
        fencebar();
    };

    for (int tt = 0; tt < NT; tt += 2) {
        tile(tt,     A0, B0, A1, B1);
        tile(tt + 1, A1, B1, A0, B0);
    }

    // epilogue: C/D col = fr (n), row = fg*4 + rr (m within 16)
#pragma unroll
    for (int i = 0; i < 8; ++i) {
#pragma unroll
        for (int j = 0; j < 4; ++j) {
            const int m = m0 + wm * 128 + i * 16 + fg * 4;
            const int n = n0 + wn * 64 + j * 16 + fr;
            float* op = out + (size_t)m * NPIX + n;
#pragma unroll
            for (int rr = 0; rr < 4; ++rr)
                op[(size_t)rr * NPIX] = acc[i][j][rr];
        }
    }
}

extern "C" void kernel_launch(void* const* d_in, const int* in_sizes, int n_in,
                              void* d_out, int out_size, void* d_ws, size_t ws_size,
                              hipStream_t stream) {
    _Float16*   pf = (_Float16*)((char*)d_ws + PF_OFF);
    _Float16*   wv = (_Float16*)((char*)d_ws + WV_OFF);

    Ptrs8 in;
    for (int i = 0; i < NV; ++i) in.p[i] = (const float*)d_in[i];

    k_prep<<<PREP_FG_BLOCKS + NPIX / 8, 256, 0, stream>>>(in, pf, wv);
    dim3 grid(NPIX / 256, NROWS / 256);   // 64 x 8 = 512 blocks
    k_gemm<<<grid, 512, 0, stream>>>(pf, wv, (float*)d_out);
}